// Round 6
// baseline (597.296 us; speedup 1.0000x reference)
//
#include <hip/hip_runtime.h>
#include <math.h>

// Mamba2: D_MODEL=1024, EXPAND=2, HEADDIM=64, NGROUPS=1, D_STATE=64,
// D_CONV=4, CHUNK=64, B=4, L=4096.
// Runtime-adaptive: fully-batched pipeline if ws_size allows (~226 MB),
// else per-batch windowed pipeline (~66 MB).  Same kernels in both modes.
#define BATCH  4
#define LSEQ   4096
#define DMODEL 1024
#define DINNER 2048
#define NH     32
#define HD     64
#define DSTATE 64
#define CONVD  2176      // D_INNER + 2*D_STATE
#define NPROJ  4352      // 34*128: z(2048) | xBC(2176) | dt(32)+pad
#define ZROW   4224      // zxbc row stride: z(2048) | xBC(2176)
#define NCHUNK 64

typedef __attribute__((ext_vector_type(8))) short bf16x8;
typedef __attribute__((ext_vector_type(4))) float f32x4;

__device__ __forceinline__ float sigm(float x){ return 1.f/(1.f+expf(-x)); }

__device__ __forceinline__ unsigned short f2bf(float x){
    unsigned u = __float_as_uint(x);
    unsigned r = (u + 0x7fffu + ((u>>16)&1u)) >> 16;
    return (unsigned short)r;
}
__device__ __forceinline__ float bf2f(unsigned short h){
    return __uint_as_float(((unsigned)h)<<16);
}

// async global (16B/lane) -> LDS (wave-uniform base + lane*16)
__device__ __forceinline__ void gl2lds16(const unsigned short* g, short* l){
    __builtin_amdgcn_global_load_lds(
        (const __attribute__((address_space(1))) unsigned int*)g,
        (__attribute__((address_space(3))) unsigned int*)l, 16, 0, 0);
}

// ---------------------------------------------------------------------------
// f32 -> bf16 streaming convert (n multiple of 8)
// ---------------------------------------------------------------------------
__global__ __launch_bounds__(256)
void f32_to_bf16(const float* __restrict__ in, unsigned short* __restrict__ o, size_t n)
{
    size_t i = ((size_t)blockIdx.x*256 + threadIdx.x)*8;
    if (i >= n) return;
    float4 a = *(const float4*)(in + i);
    float4 b = *(const float4*)(in + i + 4);
    uint4 v;
    v.x = (unsigned)f2bf(a.x) | ((unsigned)f2bf(a.y)<<16);
    v.y = (unsigned)f2bf(a.z) | ((unsigned)f2bf(a.w)<<16);
    v.z = (unsigned)f2bf(b.x) | ((unsigned)f2bf(b.y)<<16);
    v.w = (unsigned)f2bf(b.z) | ((unsigned)f2bf(b.w)<<16);
    *(uint4*)(o + i) = v;
}

// ---------------------------------------------------------------------------
// f32 -> bf16 FRAGMENT-MAJOR weight convert.
// Fragment (n16, k32) = the 16x32 B-operand tile of mfma_f32_16x16x32_bf16:
// lane = quad*16 + l15 holds B[n16*16 + l15][k32*32 + quad*8 .. +8] (16 B).
// Output address of lane-chunk = ((n16*nk32 + k32)*64 + lane)*8 = tid*8,
// so writes are perfectly linear; reads gather 8 f32 from row-major src.
// total = rows/16 * K/32 * 64 threads (rows%16==0, K%32==0).
// ---------------------------------------------------------------------------
__global__ __launch_bounds__(256)
void f32_to_bf16_frag(const float* __restrict__ in, unsigned short* __restrict__ o,
                      int K, size_t total)
{
    size_t tid = (size_t)blockIdx.x*256 + threadIdx.x;
    if (tid >= total) return;
    const int lane = (int)(tid & 63);
    const size_t rem = tid >> 6;
    const int nk32 = K >> 5;
    const int k32  = (int)(rem % nk32);
    const size_t n16 = rem / nk32;
    const float* s = in + (n16*16 + (size_t)(lane & 15))*K + k32*32 + (lane >> 4)*8;
    float4 a = *(const float4*)s;
    float4 b = *(const float4*)(s + 4);
    uint4 v;
    v.x = (unsigned)f2bf(a.x) | ((unsigned)f2bf(a.y)<<16);
    v.y = (unsigned)f2bf(a.z) | ((unsigned)f2bf(a.w)<<16);
    v.z = (unsigned)f2bf(b.x) | ((unsigned)f2bf(b.y)<<16);
    v.w = (unsigned)f2bf(b.z) | ((unsigned)f2bf(b.w)<<16);
    *(uint4*)(o + tid*8) = v;
}

// ---------------------------------------------------------------------------
// bf16 MFMA GEMM NT, 128x128 tile, BK=64, 4 waves, 4x4 x mfma 16x16x32.
// r5 post-mortem: with the T3 double-buffer the kernel sits EXACTLY on the
// LDS-read-BW roofline of the 64x64 wave tile (model 30.6%, measured 30.8%).
// This round halves LDS bytes/FLOP by taking B out of LDS:
//   * B (weights) pre-converted to FRAGMENT-MAJOR layout (f32_to_bf16_frag);
//     each lane loads its bg fragment with one coalesced global_load_dwordx4
//     (L2-hot panel, reused across the GM=16 M-group).  B traffic moves to
//     the L2 pipe (~135 B/cy/CU), parallel to LDS.
//   * LDS holds only A: 2x16 KiB dbuf -> per-block LDS reads 32KB/K-tile
//     (256 cy) vs MFMA 157 cy -> MfmaUtil ceiling ~61% (was 30.6%).
//   * bg software-pipelined one K-tile ahead in TWO NAMED register sets
//     (bgA/bgB, parity-unrolled loop; no runtime-indexed arrays).
//   * A staging identical to r5 (gl2lds + slot-XOR swizzle, 0 conflicts);
//     per-tile barrier placement identical (WAR/RAW argument unchanged).
// Math is bit-identical to r5 (same values, same accumulation order).
// EPI=0: fp32 store to Cf (ldc).  EPI=1: merged in_proj epilogue.
// ---------------------------------------------------------------------------
#define STAGEA(ktl) { \
    const int nb_ = (ktl) & 1; const int ko_ = (ktl) << 6; \
    _Pragma("unroll") for (int s=0; s<4; s++){ \
        int t_ = wave*4 + s; \
        gl2lds16(pa + (size_t)(t_*8)*lda + ko_, &As[nb_][t_*512]); \
    } }

#define LOADBG(dst, ktl) { \
    const unsigned short* fb_ = bbase + (size_t)(ktl)*1024; \
    _Pragma("unroll") for (int ks=0; ks<2; ks++) \
    _Pragma("unroll") for (int j=0; j<4; j++) \
        dst[ks*4+j] = *(const bf16x8*)(fb_ + ((size_t)j*nk32 + ks)*512); }

#define COMPUTE(Asl, bg) { \
    _Pragma("unroll") for (int ks=0; ks<2; ks++){ \
        const int co_ = ((ks*4 + quad) ^ rsw) << 3; \
        bf16x8 af[4]; \
        _Pragma("unroll") for (int i=0;i<4;i++) \
            af[i] = *(const bf16x8*)&(Asl)[(wr + i*16 + l15)*64 + co_]; \
        _Pragma("unroll") for (int i=0;i<4;i++) \
        _Pragma("unroll") for (int j=0;j<4;j++) \
            acc[i][j] = __builtin_amdgcn_mfma_f32_16x16x32_bf16(af[i], bg[ks*4+j], acc[i][j], 0,0,0); \
    } }

template<int EPI>
__global__ __launch_bounds__(256)
void gemm_mfma(const unsigned short* __restrict__ A,
               const unsigned short* __restrict__ Bf,   // fragment-major weights
               int K, int lda, int ldc, int ntiles, int Mrows,
               float* __restrict__ Cf,
               unsigned short* __restrict__ zxbc,
               float* __restrict__ dtout,
               const float* __restrict__ dt_bias,
               unsigned short* __restrict__ halo)
{
    __shared__ short As[2][128*64];   // 2 x 16 KiB, swizzled slots (A only)
    const int tid  = threadIdx.x;
    const int wave = tid >> 6;
    const int lane = tid & 63;

    // grouped swizzle: GM M-tiles per group, N-major within group
    const int GM  = 16;
    const int pid = blockIdx.x;
    const int gsz = GM * ntiles;
    const int grp = pid / gsz;
    const int rem = pid - grp*gsz;
    const int bm  = (grp*GM + (rem & (GM-1))) * 128;
    const int bn  = (rem / GM) * 128;

    const int wr = (wave >> 1) * 64;
    const int wc = (wave & 1) * 64;
    const int quad = lane >> 4;
    const int l15  = lane & 15;

    f32x4 acc[4][4];
    #pragma unroll
    for (int i=0;i<4;i++)
        #pragma unroll
        for (int j=0;j<4;j++)
            acc[i][j] = (f32x4){0.f,0.f,0.f,0.f};

    // A staging: per wave-load, 8 rows x 128 B.  lane -> row lane>>3, 16B-slot
    // lane&7.  Source col pre-swizzled so LDS holds slot^(row&7).
    const int srow8 = lane >> 3;
    const int scolx = ((lane & 7) ^ srow8) * 8;
    const int rsw   = (l15 & 7);

    const unsigned short* pa = A + (size_t)(bm + srow8)*lda + scolx;

    const int nk32 = K >> 5;
    // fragment base for this wave's 64 B-rows: frag(n16,k32) at (n16*nk32+k32)*512
    const unsigned short* bbase = Bf + ((size_t)((bn + wc) >> 4) * nk32) * 512 + lane*8;

    const int nkt = K >> 6;           // BK=64; nkt is 16 or 32 (even)

    bf16x8 bgA[8], bgB[8];

    // prologue: stage A tile0, load bg tile0, drain once
    STAGEA(0);
    LOADBG(bgA, 0);
    __syncthreads();

    for (int kt = 0; kt < nkt; kt += 2){
        // even tile kt (buf0, bgA); prefetch tile kt+1
        STAGEA(kt+1);
        LOADBG(bgB, kt+1);
        COMPUTE(As[0], bgA);
        __syncthreads();
        // odd tile kt+1 (buf1, bgB); prefetch tile kt+2
        if (kt+2 < nkt){
            STAGEA(kt+2);
            LOADBG(bgA, kt+2);
        }
        COMPUTE(As[1], bgB);
        __syncthreads();
    }

    // C/D layout: col = lane&15, row = quad*4 + reg   [m89-verified]
    if (EPI == 0){
        #pragma unroll
        for (int i=0;i<4;i++)
            #pragma unroll
            for (int j=0;j<4;j++){
                int col = bn + wc + j*16 + l15;
                #pragma unroll
                for (int r=0;r<4;r++){
                    int row = bm + wr + i*16 + quad*4 + r;
                    Cf[(size_t)row*ldc + col] = acc[i][j][r];
                }
            }
    } else {
        if (bn < DINNER){
            #pragma unroll
            for (int i=0;i<4;i++)
                #pragma unroll
                for (int r=0;r<4;r++){
                    int row = bm + wr + i*16 + quad*4 + r;
                    #pragma unroll
                    for (int j=0;j<4;j++){
                        int col = bn + wc + j*16 + l15;
                        zxbc[(size_t)row*ZROW + col] = f2bf(acc[i][j][r]);
                    }
                }
        } else if (bn < DINNER + CONVD){
            #pragma unroll
            for (int i=0;i<4;i++)
                #pragma unroll
                for (int r=0;r<4;r++){
                    int row = bm + wr + i*16 + quad*4 + r;
                    int rel = row & 63;
                    int seg = (row >> 6) + 1;
                    #pragma unroll
                    for (int j=0;j<4;j++){
                        int col = bn + wc + j*16 + l15;
                        unsigned short v = f2bf(acc[i][j][r]);
                        zxbc[(size_t)row*ZROW + col] = v;
                        if (rel >= 61 && seg*64 < Mrows)
                            halo[((size_t)(seg*3 + (rel-61)))*CONVD + (col - DINNER)] = v;
                    }
                }
        } else if (wc == 0){
            #pragma unroll
            for (int j=0;j<2;j++){
                int h = j*16 + l15;
                #pragma unroll
                for (int i=0;i<4;i++)
                    #pragma unroll
                    for (int r=0;r<4;r++){
                        int row = bm + wr + i*16 + quad*4 + r;
                        float t = acc[i][j][r] + dt_bias[h];
                        dtout[(size_t)row*NH + h] = (t > 20.f) ? t : log1pf(expf(t));
                    }
            }
        }
    }
}

// ---------------------------------------------------------------------------
// Causal conv(4) + bias + SiLU, in place, bf16.  grid (9, 64*nb); seg is the
// GLOBAL 64-row segment; batch boundaries (seg&63==0) use zero history.
// ---------------------------------------------------------------------------
__global__ __launch_bounds__(256)
void conv_inplace(unsigned short* __restrict__ zxbc,
                  const unsigned short* __restrict__ halo,
                  const float* __restrict__ conv_w, const float* __restrict__ conv_b)
{
    int c = blockIdx.x*256 + threadIdx.x;
    if (c >= CONVD) return;
    int seg = blockIdx.y;
    const float w0=conv_w[c*4+0], w1=conv_w[c*4+1], w2=conv_w[c*4+2], w3=conv_w[c*4+3];
    const float bias = conv_b[c];
    float x0=0.f, x1=0.f, x2=0.f;
    if ((seg & 63) != 0){
        const unsigned short* hp = halo + (size_t)(seg*3)*CONVD + c;
        x0 = bf2f(hp[0]); x1 = bf2f(hp[CONVD]); x2 = bf2f(hp[2*CONVD]);
    }
    unsigned short* p = zxbc + (size_t)(seg*64)*ZROW + DINNER + c;
    for (int i=0;i<64;i++){
        float x3 = bf2f(*p);
        float v = fmaf(w0,x0,fmaf(w1,x1,fmaf(w2,x2,fmaf(w3,x3,bias))));
        *p = f2bf(v * sigm(v));
        x0=x1; x1=x2; x2=x3; p += ZROW;
    }
}

// ---------------------------------------------------------------------------
// states_intra: grid (NH, nchunks) [h fastest -> L2 reuse of B/x rows].
// loc_state[p][n] = sum_l x[l][p]*dt[l]*dec[l]*B[l][n] via NT MFMA.
// ---------------------------------------------------------------------------
__global__ __launch_bounds__(256)
void states_intra(const unsigned short* __restrict__ zxbc,
                  const float* __restrict__ dtbuf,
                  const float* __restrict__ A_log,
                  unsigned short* __restrict__ locst,
                  float* __restrict__ acsbuf,
                  float* __restrict__ csumbuf)
{
    const int h = blockIdx.x, c = blockIdx.y;
    __shared__ unsigned short XT[64*72];   // XT[p][l] = x[l][p]
    __shared__ unsigned short BT[64*72];   // BT[n][l] = B[l][n]*dec[l]*dt[l]
    __shared__ float dt_sh[64], acs_sh[64], w_sh[64];
    const int tid = threadIdx.x;
    const size_t row0 = (size_t)(c*64)*ZROW;

    if (tid < 64) dt_sh[tid] = dtbuf[(size_t)(c*64+tid)*NH + h];
    __syncthreads();
    if (tid == 0){
        float Ah = -expf(A_log[h]); float s = 0.f;
        for (int l=0;l<64;l++){ s = fmaf(Ah, dt_sh[l], s); acs_sh[l] = s; }
    }
    __syncthreads();
    const float a63 = acs_sh[63];
    if (tid < 64){
        float a = acs_sh[tid];
        acsbuf[((size_t)c*NH + h)*64 + tid] = a;
        w_sh[tid] = expf(a63 - a) * dt_sh[tid];
    }
    if (tid == 0) csumbuf[(size_t)c*NH + h] = a63;
    __syncthreads();

    {
        const int l  = tid >> 2;
        const int f4 = tid & 3;
        const unsigned short* xr = zxbc + row0 + (size_t)l*ZROW;
        const float w = w_sh[l];
        #pragma unroll
        for (int q=0;q<4;q++){
            int col = f4*4 + q*16;
            uint2 xv = *(const uint2*)(xr + DINNER + h*HD + col);
            uint2 bv = *(const uint2*)(xr + DINNER + DINNER + col);
            XT[(col+0)*72 + l] = (unsigned short)(xv.x & 0xffff);
            XT[(col+1)*72 + l] = (unsigned short)(xv.x >> 16);
            XT[(col+2)*72 + l] = (unsigned short)(xv.y & 0xffff);
            XT[(col+3)*72 + l] = (unsigned short)(xv.y >> 16);
            BT[(col+0)*72 + l] = f2bf(bf2f((unsigned short)(bv.x & 0xffff))*w);
            BT[(col+1)*72 + l] = f2bf(bf2f((unsigned short)(bv.x >> 16))*w);
            BT[(col+2)*72 + l] = f2bf(bf2f((unsigned short)(bv.y & 0xffff))*w);
            BT[(col+3)*72 + l] = f2bf(bf2f((unsigned short)(bv.y >> 16))*w);
        }
    }
    __syncthreads();

    const int wave = tid >> 6, lane = tid & 63;
    const int quad = lane >> 4, l15 = lane & 15;
    f32x4 acc[4];
    #pragma unroll
    for (int j=0;j<4;j++) acc[j] = (f32x4){0.f,0.f,0.f,0.f};
    #pragma unroll
    for (int ks=0;ks<2;ks++){
        bf16x8 af = *(const bf16x8*)&XT[(wave*16 + l15)*72 + ks*32 + quad*8];
        #pragma unroll
        for (int j=0;j<4;j++){
            bf16x8 bf = *(const bf16x8*)&BT[(j*16 + l15)*72 + ks*32 + quad*8];
            acc[j] = __builtin_amdgcn_mfma_f32_16x16x32_bf16(af, bf, acc[j], 0,0,0);
        }
    }
    const size_t sbase = ((size_t)c*NH + h)*4096;
    #pragma unroll
    for (int j=0;j<4;j++)
        #pragma unroll
        for (int r=0;r<4;r++){
            int p = wave*16 + quad*4 + r;
            int n = j*16 + l15;
            locst[sbase + (size_t)p*64 + n] = f2bf(acc[j][r]);
        }
}

// ---------------------------------------------------------------------------
// Inter-chunk scan, in place (loc -> entering), grid (NH, 2, nb).
// ---------------------------------------------------------------------------
__global__ __launch_bounds__(256)
void chunk_scan(unsigned short* __restrict__ states,
                const float* __restrict__ csumbuf,
                const float* __restrict__ init_states)
{
    const int h = blockIdx.x, half = blockIdx.y, b = blockIdx.z;
    __shared__ float cs_sh[64];
    const int tid = threadIdx.x;
    if (tid < 64) cs_sh[tid] = csumbuf[(size_t)(b*64 + tid)*NH + h];
    __syncthreads();
    const int e0 = half*2048 + tid*8;
    float S[8];
    {
        const float4* ip = (const float4*)(init_states + (size_t)h*4096 + e0);
        float4 v0 = ip[0], v1 = ip[1];
        S[0]=v0.x; S[1]=v0.y; S[2]=v0.z; S[3]=v0.w;
        S[4]=v1.x; S[5]=v1.y; S[6]=v1.z; S[7]=v1.w;
    }
    for (int zg=0; zg<8; zg++){
        uint4 L[8];
        #pragma unroll
        for (int k=0;k<8;k++)
            L[k] = *(const uint4*)(states + ((size_t)(b*64 + zg*8+k)*NH + h)*4096 + e0);
        #pragma unroll
        for (int k=0;k<8;k++){
            int z = zg*8 + k;
            float dec = expf(cs_sh[z]);
            uint4 o;
            o.x = (unsigned)f2bf(S[0]) | ((unsigned)f2bf(S[1])<<16);
            o.y = (unsigned)f2bf(S[2]) | ((unsigned)f2bf(S[3])<<16);
            o.z = (unsigned)f2bf(S[4]) | ((unsigned)f2bf(S[5])<<16);
            o.w = (unsigned)f2bf(S[6]) | ((unsigned)f2bf(S[7])<<16);
            *(uint4*)(states + ((size_t)(b*64 + z)*NH + h)*4096 + e0) = o;
            unsigned a[4] = {L[k].x, L[k].y, L[k].z, L[k].w};
            #pragma unroll
            for (int q=0;q<4;q++){
                float lo = bf2f((unsigned short)(a[q]&0xffff));
                float hi = bf2f((unsigned short)(a[q]>>16));
                S[q*2+0] = fmaf(dec, S[q*2+0], lo);
                S[q*2+1] = fmaf(dec, S[q*2+1], hi);
            }
        }
    }
}

// ---------------------------------------------------------------------------
// y_fused: grid (NH, nchunks).  G = C·B^T (MFMA) -> score (mask/decay/dt,
// +D on diag) -> Y = score·x + (ea·C)·S_enter^T, single bf16 write.
// ---------------------------------------------------------------------------
__global__ __launch_bounds__(256)
void y_fused(unsigned short* __restrict__ zxbc,
             const float* __restrict__ dtbuf,
             const unsigned short* __restrict__ entst,
             const float* __restrict__ acsbuf,
             const float* __restrict__ Dvec)
{
    const int h = blockIdx.x, c = blockIdx.y;
    __shared__ unsigned short Cr[64*72];
    __shared__ unsigned short Ce[64*72];
    __shared__ unsigned short Bm[64*72];   // B raw; reused for score
    __shared__ unsigned short XT[64*72];
    __shared__ unsigned short Sv[64*72];
    __shared__ float acs_sh[64], dt_sh[64], ea_sh[64];
    const int tid = threadIdx.x;
    const size_t row0 = (size_t)(c*64)*ZROW;
    const size_t sbase = ((size_t)c*NH + h)*4096;

    if (tid < 64){
        float a = acsbuf[((size_t)c*NH + h)*64 + tid];
        acs_sh[tid] = a;
        ea_sh[tid]  = expf(a);
        dt_sh[tid]  = dtbuf[(size_t)(c*64 + tid)*NH + h];
    }
    __syncthreads();

    {
        const int l  = tid >> 2;
        const int f4 = tid & 3;
        const unsigned short* xr = zxbc + row0 + (size_t)l*ZROW;
        const float el = ea_sh[l];
        #pragma unroll
        for (int q=0;q<4;q++){
            int col = f4*4 + q*16;
            uint2 cv = *(const uint2*)(xr + DINNER + DINNER + DSTATE + col);
            uint2 bv = *(const uint2*)(xr + DINNER + DINNER + col);
            uint2 xv = *(const uint2*)(xr + DINNER + h*HD + col);
            *(uint2*)&Cr[l*72 + col] = cv;
            *(uint2*)&Bm[l*72 + col] = bv;
            unsigned short* ce = &Ce[l*72 + col];
            ce[0] = f2bf(bf2f((unsigned short)(cv.x & 0xffff))*el);
            ce[1] = f2bf(bf2f((unsigned short)(cv.x >> 16))*el);
            ce[2] = f2bf(bf2f((unsigned short)(cv.y & 0xffff))*el);
            ce[3] = f2bf(bf2f((unsigned short)(cv.y >> 16))*el);
            XT[(col+0)*72 + l] = (unsigned short)(xv.x & 0xffff);
            XT[(col+1)*72 + l] = (unsigned short)(xv.x >> 16);
            XT[(col+2)*72 + l] = (unsigned short)(xv.y & 0xffff);
            XT[(col+3)*72 + l] = (unsigned short)(xv.y >> 16);
            *(uint2*)&Sv[l*72 + col] = *(const uint2*)(entst + sbase + (size_t)l*64 + col);
        }
    }
    __syncthreads();

    const int wave = tid >> 6, lane = tid & 63;
    const int quad = lane >> 4, l15 = lane & 15;

    f32x4 g[4];
    #pragma unroll
    for (int j=0;j<4;j++) g[j] = (f32x4){0.f,0.f,0.f,0.f};
    #pragma unroll
    for (int ks=0;ks<2;ks++){
        bf16x8 af = *(const bf16x8*)&Cr[(wave*16 + l15)*72 + ks*32 + quad*8];
        #pragma unroll
        for (int j=0;j<4;j++){
            bf16x8 bf = *(const bf16x8*)&Bm[(j*16 + l15)*72 + ks*32 + quad*8];
            g[j] = __builtin_amdgcn_mfma_f32_16x16x32_bf16(af, bf, g[j], 0,0,0);
        }
    }
    __syncthreads();

    const float Dh = Dvec[h];
    #pragma unroll
    for (int j=0;j<4;j++)
        #pragma unroll
        for (int r=0;r<4;r++){
            int l = wave*16 + quad*4 + r;
            int s = j*16 + l15;
            float v = (s <= l) ? g[j][r]*expf(acs_sh[l]-acs_sh[s])*dt_sh[s] : 0.f;
            if (s == l) v += Dh;
            Bm[l*72 + s] = f2bf(v);
        }
    __syncthreads();

    f32x4 y[4];
    #pragma unroll
    for (int j=0;j<4;j++) y[j] = (f32x4){0.f,0.f,0.f,0.f};
    #pragma unroll
    for (int ks=0;ks<2;ks++){
        bf16x8 a1 = *(const bf16x8*)&Bm[(wave*16 + l15)*72 + ks*32 + quad*8];
        bf16x8 a2 = *(const bf16x8*)&Ce[(wave*16 + l15)*72 + ks*32 + quad*8];
        #pragma unroll
        for (int j=0;j<4;j++){
            bf16x8 b1 = *(const bf16x8*)&XT[(j*16 + l15)*72 + ks*32 + quad*8];
            bf16x8 b2 = *(const bf16x8*)&Sv[(j*16 + l15)*72 + ks*32 + quad*8];
            y[j] = __builtin_amdgcn_mfma_f32_16x16x32_bf16(a1, b1, y[j], 0,0,0);
            y[j] = __builtin_amdgcn_mfma_f32_16x16x32_bf16(a2, b2, y[j], 0,0,0);
        }
    }

    #pragma unroll
    for (int j=0;j<4;j++)
        #pragma unroll
        for (int r=0;r<4;r++){
            int l = wave*16 + quad*4 + r;
            int p = j*16 + l15;
            zxbc[row0 + (size_t)l*ZROW + DINNER + h*HD + p] = f2bf(y[j][r]);
        }
}

// ---------------------------------------------------------------------------
// gate + RMSNorm: y = RMSNorm(Y*silu(z))*w; writes y bf16 over z cols.
// ---------------------------------------------------------------------------
__global__ __launch_bounds__(256)
void gate_norm(unsigned short* __restrict__ zxbc, const float* __restrict__ norm_w)
{
    const int m = blockIdx.x;
    const int tid = threadIdx.x;
    unsigned short* row = zxbc + (size_t)m*ZROW;
    uint4 zv = *(const uint4*)(row + tid*8);
    uint4 yv = *(const uint4*)(row + DINNER + tid*8);
    unsigned zz[4] = {zv.x, zv.y, zv.z, zv.w};
    unsigned yy[4] = {yv.x, yv.y, yv.z, yv.w};
    float g[8];
    float acc = 0.f;
    #pragma unroll
    for (int q=0;q<4;q++){
        float zl = bf2f((unsigned short)(zz[q]&0xffff));
        float zh = bf2f((unsigned short)(zz[q]>>16));
        float yl = bf2f((unsigned short)(yy[q]&0xffff));
        float yh = bf2f((unsigned short)(yy[q]>>16));
        g[q*2+0] = yl * zl * sigm(zl);
        g[q*2+1] = yh * zh * sigm(zh);
        acc += g[q*2]*g[q*2] + g[q*2+1]*g[q*2+1];
    }
    #pragma unroll
    for (int o=32;o>0;o>>=1) acc += __shfl_down(acc, o, 64);
    __shared__ float red[4];
    if ((tid & 63)==0) red[tid>>6] = acc;
    __syncthreads();
    float tot = red[0]+red[1]+red[2]+red[3];
    float scale = rsqrtf(tot * (1.f/2048.f) + 1e-5f);
    const float* nw = norm_w + tid*8;
    float4 w0 = *(const float4*)nw;
    float4 w1 = *(const float4*)(nw+4);
    float Wv[8] = {w0.x,w0.y,w0.z,w0.w,w1.x,w1.y,w1.z,w1.w};
    uint4 ov;
    unsigned ow[4];
    #pragma unroll
    for (int q=0;q<4;q++){
        unsigned short lo = f2bf(g[q*2+0]*scale*Wv[q*2+0]);
        unsigned short hi = f2bf(g[q*2+1]*scale*Wv[q*2+1]);
        ow[q] = (unsigned)lo | ((unsigned)hi<<16);
    }
    ov.x=ow[0]; ov.y=ow[1]; ov.z=ow[2]; ov.w=ow[3];
    *(uint4*)(row + tid*8) = ov;
}

// ---------------------------------------------------------------------------
extern "C" void kernel_launch(void* const* d_in, const int* in_sizes, int n_in,
                              void* d_out, int out_size, void* d_ws, size_t ws_size,
                              hipStream_t stream) {
    const float* u           = (const float*)d_in[0];
    const float* in_proj_w   = (const float*)d_in[1];
    const float* conv_w      = (const float*)d_in[2];
    const float* conv_b      = (const float*)d_in[3];
    const float* init_states = (const float*)d_in[4];
    const float* dt_bias     = (const float*)d_in[5];
    const float* A_log       = (const float*)d_in[6];
    const float* Dv          = (const float*)d_in[7];
    const float* norm_w      = (const float*)d_in[8];
    const float* out_proj_w  = (const float*)d_in[9];
    float* out = (float*)d_out;
    char* wsb = (char*)d_ws;

    // BIG layout (~226 MB): all 4 batches in one pipeline.
    // SMALL layout (~66 MB): per-batch windows (proven envelope).
    const size_t BIG_BYTES = 226197504;
    const bool big = (ws_size >= BIG_BYTES);
    const int nb = big ? BATCH : 1;
    const size_t Mrows = (size_t)nb * LSEQ;          // rows per pipeline pass

    size_t off = 0;
    unsigned short* zxbc    = (unsigned short*)(wsb + off); off += Mrows*ZROW*2;
    unsigned short* statesz = (unsigned short*)(wsb + off);
    unsigned short* ubf     = statesz;               // alias: dead before states written
    off += Mrows/64 * NH*HD*DSTATE*2;                // nb*16.78MB
    unsigned short* wibf    = (unsigned short*)(wsb + off); off += (size_t)NPROJ*DMODEL*2;
    unsigned short* woutbf  = (unsigned short*)(wsb + off); off += (size_t)DMODEL*DINNER*2;
    float*          dtbuf   = (float*)(wsb + off);   off += Mrows*NH*4;
    float*          acsbuf  = (float*)(wsb + off);   off += Mrows/64 * NH*64*4;
    float*          csumbuf = (float*)(wsb + off);   off += Mrows/64 * NH*4;
    unsigned short* halo    = (unsigned short*)(wsb + off); off += Mrows/64 * 3*CONVD*2;

    // weights -> bf16 FRAGMENT-MAJOR (once).  in_proj: rows 0..4255 converted
    // (266 n16-groups); fragments for n16 266..271 (rows 4256..4351) stay
    // uninitialized -- read by tile 33 but those acc cols are never stored.
    f32_to_bf16_frag<<<dim3(2128), 256, 0, stream>>>(
        in_proj_w, wibf, DMODEL, (size_t)266*32*64);
    f32_to_bf16_frag<<<dim3(1024), 256, 0, stream>>>(
        out_proj_w, woutbf, DINNER, (size_t)64*64*64);

    const int npass = big ? 1 : BATCH;
    for (int b=0; b<npass; b++){
        const float* ub   = u   + (size_t)b*LSEQ*DMODEL;
        float*       outb = out + (size_t)b*LSEQ*DMODEL;
        const int mt = (int)(Mrows/128);             // M tiles per pass

        // 0) u -> bf16
        f32_to_bf16<<<dim3(Mrows*DMODEL/8/256), 256, 0, stream>>>(
            ub, ubf, Mrows*DMODEL);
        // 1) merged in_proj (z + xBC + dt) + halo + softplus, grouped swizzle
        gemm_mfma<1><<<dim3((NPROJ/128) * mt), 256, 0, stream>>>(
            ubf, wibf, DMODEL, DMODEL, 0, NPROJ/128, (int)Mrows,
            nullptr, zxbc, dtbuf, dt_bias, halo);
        // 2) causal conv + silu in place
        conv_inplace<<<dim3(9, (unsigned)(Mrows/64)), 256, 0, stream>>>(
            zxbc, halo, conv_w, conv_b);
        // 3) local states (MFMA) + acs/csum
        states_intra<<<dim3(NH, (unsigned)(Mrows/64)), 256, 0, stream>>>(
            zxbc, dtbuf, A_log, statesz, acsbuf, csumbuf);
        // 4) inter-chunk scan in place (loc -> entering)
        chunk_scan<<<dim3(NH, 2, nb), 256, 0, stream>>>(
            statesz, csumbuf, init_states);
        // 5) fused Y = Y_diag + Y_off + x*D
        y_fused<<<dim3(NH, (unsigned)(Mrows/64)), 256, 0, stream>>>(
            zxbc, dtbuf, statesz, acsbuf, Dv);
        // 6) gate + RMSNorm -> y bf16 over z cols
        gate_norm<<<dim3((unsigned)Mrows), 256, 0, stream>>>(zxbc, norm_w);
        // 7) out_proj -> out fp32, grouped swizzle
        gemm_mfma<0><<<dim3((DMODEL/128) * mt), 256, 0, stream>>>(
            zxbc, woutbf, DINNER, ZROW, DMODEL, DMODEL/128, (int)Mrows,
            outb, nullptr, nullptr, nullptr, nullptr);
    }
}

// Round 7
// 576.473 us; speedup vs baseline: 1.0361x; 1.0361x over previous
//
#include <hip/hip_runtime.h>
#include <math.h>

// Mamba2: D_MODEL=1024, EXPAND=2, HEADDIM=64, NGROUPS=1, D_STATE=64,
// D_CONV=4, CHUNK=64, B=4, L=4096.
// Runtime-adaptive: fully-batched pipeline if ws_size allows (~226 MB),
// else per-batch windowed pipeline (~66 MB).  Same kernels in both modes.
#define BATCH  4
#define LSEQ   4096
#define DMODEL 1024
#define DINNER 2048
#define NH     32
#define HD     64
#define DSTATE 64
#define CONVD  2176      // D_INNER + 2*D_STATE
#define NPROJ  4352      // 34*128: z(2048) | xBC(2176) | dt(32)+pad
#define ZROW   4224      // zxbc row stride: z(2048) | xBC(2176)
#define NCHUNK 64

typedef __attribute__((ext_vector_type(8))) short bf16x8;
typedef __attribute__((ext_vector_type(4))) float f32x4;

__device__ __forceinline__ float sigm(float x){ return 1.f/(1.f+expf(-x)); }

__device__ __forceinline__ unsigned short f2bf(float x){
    unsigned u = __float_as_uint(x);
    unsigned r = (u + 0x7fffu + ((u>>16)&1u)) >> 16;
    return (unsigned short)r;
}
__device__ __forceinline__ float bf2f(unsigned short h){
    return __uint_as_float(((unsigned)h)<<16);
}

// async global (16B/lane) -> LDS (wave-uniform base + lane*16)
__device__ __forceinline__ void gl2lds16(const unsigned short* g, short* l){
    __builtin_amdgcn_global_load_lds(
        (const __attribute__((address_space(1))) unsigned int*)g,
        (__attribute__((address_space(3))) unsigned int*)l, 16, 0, 0);
}

// ---------------------------------------------------------------------------
// f32 -> bf16 streaming convert (n multiple of 8)
// ---------------------------------------------------------------------------
__global__ __launch_bounds__(256)
void f32_to_bf16(const float* __restrict__ in, unsigned short* __restrict__ o, size_t n)
{
    size_t i = ((size_t)blockIdx.x*256 + threadIdx.x)*8;
    if (i >= n) return;
    float4 a = *(const float4*)(in + i);
    float4 b = *(const float4*)(in + i + 4);
    uint4 v;
    v.x = (unsigned)f2bf(a.x) | ((unsigned)f2bf(a.y)<<16);
    v.y = (unsigned)f2bf(a.z) | ((unsigned)f2bf(a.w)<<16);
    v.z = (unsigned)f2bf(b.x) | ((unsigned)f2bf(b.y)<<16);
    v.w = (unsigned)f2bf(b.z) | ((unsigned)f2bf(b.w)<<16);
    *(uint4*)(o + i) = v;
}

// ---------------------------------------------------------------------------
// bf16 MFMA GEMM NT, 128x128 tile, BK=64, 4 waves, 4x4 x mfma 16x16x32.
// r5 SETTLED STRUCTURE (r6's B-from-L2 arm regressed and is reverted):
// T3 minimum-2-phase double-buffer -- LDS 2x(16+16) KiB; stage of tile t+1
// issued BEFORE ds_read+MFMA of tile t; ONE __syncthreads per K-tile.
// Sits on the measured LDS-read-BW roofline of the 64x64 wave tile
// (model 30.6% MfmaUtil, measured 30.8%).  Slot-XOR swizzle: 0 conflicts.
// EPI=0: fp32 store to Cf (ldc).  EPI=1: merged in_proj epilogue:
//   tiles 0..15 -> z bf16, 16..32 -> xBC bf16 + conv halo, 33 -> dt.
// ---------------------------------------------------------------------------
template<int EPI>
__global__ __launch_bounds__(256)
void gemm_mfma(const unsigned short* __restrict__ A,
               const unsigned short* __restrict__ B,
               int K, int lda, int ldc, int ntiles, int Mrows,
               float* __restrict__ Cf,
               unsigned short* __restrict__ zxbc,
               float* __restrict__ dtout,
               const float* __restrict__ dt_bias,
               unsigned short* __restrict__ halo)
{
    __shared__ short As[2][128*64];   // 2 x 16 KiB, swizzled slots
    __shared__ short Bs[2][128*64];   // 2 x 16 KiB
    const int tid  = threadIdx.x;
    const int wave = tid >> 6;
    const int lane = tid & 63;

    // grouped swizzle: GM M-tiles per group, N-major within group
    const int GM  = 16;
    const int pid = blockIdx.x;
    const int gsz = GM * ntiles;
    const int grp = pid / gsz;
    const int rem = pid - grp*gsz;
    const int bm  = (grp*GM + (rem & (GM-1))) * 128;
    const int bn  = (rem / GM) * 128;

    const int wr = (wave >> 1) * 64;
    const int wc = (wave & 1) * 64;
    const int quad = lane >> 4;
    const int l15  = lane & 15;

    f32x4 acc[4][4];
    #pragma unroll
    for (int i=0;i<4;i++)
        #pragma unroll
        for (int j=0;j<4;j++)
            acc[i][j] = (f32x4){0.f,0.f,0.f,0.f};

    // staging: per wave-load, 8 rows x 128 B.  lane -> row lane>>3, 16B-slot
    // lane&7.  Source col pre-swizzled so LDS holds slot^(row&7).
    const int srow8 = lane >> 3;                  // 0..7: row within group
    const int scolx = ((lane & 7) ^ srow8) * 8;   // swizzled source col (shorts)
    const int rsw   = (l15 & 7);                  // read-side XOR key (= row&7)

    const unsigned short* pa = A + (size_t)(bm + srow8)*lda + scolx;
    const unsigned short* pb = B + (size_t)(bn + srow8)*K   + scolx;

    const int nkt = K >> 6;           // BK=64

    // prologue: stage tile 0 into buf 0, drain once
    #pragma unroll
    for (int s=0; s<4; s++){
        int t = wave*4 + s;
        gl2lds16(pa + (size_t)(t*8)*lda, &As[0][t*512]);
        gl2lds16(pb + (size_t)(t*8)*K,   &Bs[0][t*512]);
    }
    __syncthreads();

    for (int kt = 0; kt < nkt; ++kt){
        // issue next tile's stage FIRST (overlaps with ds_read+MFMA below)
        if (kt+1 < nkt){
            const int nb_ = (kt+1) & 1;
            const int ko  = (kt+1) << 6;
            #pragma unroll
            for (int s=0; s<4; s++){
                int t = wave*4 + s;
                gl2lds16(pa + (size_t)(t*8)*lda + ko, &As[nb_][t*512]);
                gl2lds16(pb + (size_t)(t*8)*K   + ko, &Bs[nb_][t*512]);
            }
        }
        const short* Asl = &As[kt & 1][0];
        const short* Bsl = &Bs[kt & 1][0];
        #pragma unroll
        for (int ks=0; ks<2; ks++){
            const int co = ((ks*4 + quad) ^ rsw) << 3;
            bf16x8 af[4], bg[4];
            #pragma unroll
            for (int i=0;i<4;i++)
                af[i] = *(const bf16x8*)&Asl[(wr + i*16 + l15)*64 + co];
            #pragma unroll
            for (int j=0;j<4;j++)
                bg[j] = *(const bf16x8*)&Bsl[(wc + j*16 + l15)*64 + co];
            #pragma unroll
            for (int i=0;i<4;i++)
                #pragma unroll
                for (int j=0;j<4;j++)
                    acc[i][j] = __builtin_amdgcn_mfma_f32_16x16x32_bf16(af[i], bg[j], acc[i][j], 0,0,0);
        }
        // single barrier per tile: drains vmcnt (next tile staged above,
        // latency already covered by compute) + makes buf visible
        __syncthreads();
    }

    // C/D layout: col = lane&15, row = quad*4 + reg   [m89-verified]
    if (EPI == 0){
        #pragma unroll
        for (int i=0;i<4;i++)
            #pragma unroll
            for (int j=0;j<4;j++){
                int col = bn + wc + j*16 + l15;
                #pragma unroll
                for (int r=0;r<4;r++){
                    int row = bm + wr + i*16 + quad*4 + r;
                    Cf[(size_t)row*ldc + col] = acc[i][j][r];
                }
            }
    } else {
        if (bn < DINNER){
            #pragma unroll
            for (int i=0;i<4;i++)
                #pragma unroll
                for (int r=0;r<4;r++){
                    int row = bm + wr + i*16 + quad*4 + r;
                    #pragma unroll
                    for (int j=0;j<4;j++){
                        int col = bn + wc + j*16 + l15;
                        zxbc[(size_t)row*ZROW + col] = f2bf(acc[i][j][r]);
                    }
                }
        } else if (bn < DINNER + CONVD){
            #pragma unroll
            for (int i=0;i<4;i++)
                #pragma unroll
                for (int r=0;r<4;r++){
                    int row = bm + wr + i*16 + quad*4 + r;
                    int rel = row & 63;
                    int seg = (row >> 6) + 1;
                    #pragma unroll
                    for (int j=0;j<4;j++){
                        int col = bn + wc + j*16 + l15;
                        unsigned short v = f2bf(acc[i][j][r]);
                        zxbc[(size_t)row*ZROW + col] = v;
                        if (rel >= 61 && seg*64 < Mrows)
                            halo[((size_t)(seg*3 + (rel-61)))*CONVD + (col - DINNER)] = v;
                    }
                }
        } else if (wc == 0){
            #pragma unroll
            for (int j=0;j<2;j++){
                int h = j*16 + l15;
                #pragma unroll
                for (int i=0;i<4;i++)
                    #pragma unroll
                    for (int r=0;r<4;r++){
                        int row = bm + wr + i*16 + quad*4 + r;
                        float t = acc[i][j][r] + dt_bias[h];
                        dtout[(size_t)row*NH + h] = (t > 20.f) ? t : log1pf(expf(t));
                    }
            }
        }
    }
}

// ---------------------------------------------------------------------------
// Causal conv(4) + bias + SiLU, in place, bf16.  grid (9, 64*nb); seg is the
// GLOBAL 64-row segment; batch boundaries (seg&63==0) use zero history.
// ---------------------------------------------------------------------------
__global__ __launch_bounds__(256)
void conv_inplace(unsigned short* __restrict__ zxbc,
                  const unsigned short* __restrict__ halo,
                  const float* __restrict__ conv_w, const float* __restrict__ conv_b)
{
    int c = blockIdx.x*256 + threadIdx.x;
    if (c >= CONVD) return;
    int seg = blockIdx.y;
    const float w0=conv_w[c*4+0], w1=conv_w[c*4+1], w2=conv_w[c*4+2], w3=conv_w[c*4+3];
    const float bias = conv_b[c];
    float x0=0.f, x1=0.f, x2=0.f;
    if ((seg & 63) != 0){
        const unsigned short* hp = halo + (size_t)(seg*3)*CONVD + c;
        x0 = bf2f(hp[0]); x1 = bf2f(hp[CONVD]); x2 = bf2f(hp[2*CONVD]);
    }
    unsigned short* p = zxbc + (size_t)(seg*64)*ZROW + DINNER + c;
    for (int i=0;i<64;i++){
        float x3 = bf2f(*p);
        float v = fmaf(w0,x0,fmaf(w1,x1,fmaf(w2,x2,fmaf(w3,x3,bias))));
        *p = f2bf(v * sigm(v));
        x0=x1; x1=x2; x2=x3; p += ZROW;
    }
}

// ---------------------------------------------------------------------------
// states_intra MULTI-HEAD: grid (NH/4, nchunks); block handles 4 heads of
// one chunk.  NGROUPS=1 => B is head-invariant: raw transposed BT staged
// ONCE per block (was re-staged+scaled per head = 32x redundant).  The
// per-head decay*dt weight w[l] folds into the per-head XT staging instead
// (K-dim scale; mathematically identical product).  acs cumsum: per-wave
// __shfl_up inclusive scan (wave w = head hg*4+w) replaces the tid==0
// serial 64-fmaf (64 idle lanes between barriers).
// loc_state[p][n] = sum_l x[l][p]*w[l]*B[l][n] via NT MFMA.
// ---------------------------------------------------------------------------
__global__ __launch_bounds__(256)
void states_intra(const unsigned short* __restrict__ zxbc,
                  const float* __restrict__ dtbuf,
                  const float* __restrict__ A_log,
                  unsigned short* __restrict__ locst,
                  float* __restrict__ acsbuf,
                  float* __restrict__ csumbuf)
{
    const int hg = blockIdx.x, c = blockIdx.y;
    __shared__ unsigned short BT[64*72];    // BT[n][l] = B[l][n]  (raw, shared)
    __shared__ unsigned short XTw[64*72];   // XTw[p][l] = x[l][p]*w[l] (per head)
    __shared__ float w_sh4[4][64];
    const int tid  = threadIdx.x;
    const int wave = tid >> 6, lane = tid & 63;
    const size_t row0 = (size_t)(c*64)*ZROW;

    // shared: raw B transpose
    {
        const int l  = tid >> 2;
        const int f4 = tid & 3;
        const unsigned short* xr = zxbc + row0 + (size_t)l*ZROW + DINNER + DINNER;
        #pragma unroll
        for (int q=0;q<4;q++){
            int col = f4*4 + q*16;
            uint2 bv = *(const uint2*)(xr + col);
            BT[(col+0)*72 + l] = (unsigned short)(bv.x & 0xffff);
            BT[(col+1)*72 + l] = (unsigned short)(bv.x >> 16);
            BT[(col+2)*72 + l] = (unsigned short)(bv.y & 0xffff);
            BT[(col+3)*72 + l] = (unsigned short)(bv.y >> 16);
        }
    }
    // per-wave scan: wave handles head hg*4+wave
    {
        const int h = hg*4 + wave;
        float dt = dtbuf[(size_t)(c*64 + lane)*NH + h];
        float Ah = -expf(A_log[h]);
        float s  = Ah * dt;
        #pragma unroll
        for (int o=1; o<64; o<<=1){
            float t = __shfl_up(s, o, 64);
            if (lane >= o) s += t;
        }
        float a63 = __shfl(s, 63, 64);
        acsbuf[((size_t)c*NH + h)*64 + lane] = s;
        w_sh4[wave][lane] = expf(a63 - s) * dt;
        if (lane == 0) csumbuf[(size_t)c*NH + h] = a63;
    }
    __syncthreads();

    const int quad = lane >> 4, l15 = lane & 15;
    for (int hh=0; hh<4; hh++){
        const int h = hg*4 + hh;
        if (hh) __syncthreads();          // prev head's MFMA reads of XTw done
        {
            const int l  = tid >> 2;
            const int f4 = tid & 3;
            const unsigned short* xr = zxbc + row0 + (size_t)l*ZROW + DINNER + h*HD;
            const float w = w_sh4[hh][l];
            #pragma unroll
            for (int q=0;q<4;q++){
                int col = f4*4 + q*16;
                uint2 xv = *(const uint2*)(xr + col);
                XTw[(col+0)*72 + l] = f2bf(bf2f((unsigned short)(xv.x & 0xffff))*w);
                XTw[(col+1)*72 + l] = f2bf(bf2f((unsigned short)(xv.x >> 16))*w);
                XTw[(col+2)*72 + l] = f2bf(bf2f((unsigned short)(xv.y & 0xffff))*w);
                XTw[(col+3)*72 + l] = f2bf(bf2f((unsigned short)(xv.y >> 16))*w);
            }
        }
        __syncthreads();
        f32x4 acc[4];
        #pragma unroll
        for (int j=0;j<4;j++) acc[j] = (f32x4){0.f,0.f,0.f,0.f};
        #pragma unroll
        for (int ks=0;ks<2;ks++){
            bf16x8 af = *(const bf16x8*)&XTw[(wave*16 + l15)*72 + ks*32 + quad*8];
            #pragma unroll
            for (int j=0;j<4;j++){
                bf16x8 bf = *(const bf16x8*)&BT[(j*16 + l15)*72 + ks*32 + quad*8];
                acc[j] = __builtin_amdgcn_mfma_f32_16x16x32_bf16(af, bf, acc[j], 0,0,0);
            }
        }
        const size_t sbase = ((size_t)c*NH + h)*4096;
        #pragma unroll
        for (int j=0;j<4;j++)
            #pragma unroll
            for (int r=0;r<4;r++){
                int p = wave*16 + quad*4 + r;
                int n = j*16 + l15;
                locst[sbase + (size_t)p*64 + n] = f2bf(acc[j][r]);
            }
    }
}

// ---------------------------------------------------------------------------
// Inter-chunk scan, in place (loc -> entering), grid (NH, 2, nb).
// ---------------------------------------------------------------------------
__global__ __launch_bounds__(256)
void chunk_scan(unsigned short* __restrict__ states,
                const float* __restrict__ csumbuf,
                const float* __restrict__ init_states)
{
    const int h = blockIdx.x, half = blockIdx.y, b = blockIdx.z;
    __shared__ float cs_sh[64];
    const int tid = threadIdx.x;
    if (tid < 64) cs_sh[tid] = csumbuf[(size_t)(b*64 + tid)*NH + h];
    __syncthreads();
    const int e0 = half*2048 + tid*8;
    float S[8];
    {
        const float4* ip = (const float4*)(init_states + (size_t)h*4096 + e0);
        float4 v0 = ip[0], v1 = ip[1];
        S[0]=v0.x; S[1]=v0.y; S[2]=v0.z; S[3]=v0.w;
        S[4]=v1.x; S[5]=v1.y; S[6]=v1.z; S[7]=v1.w;
    }
    for (int zg=0; zg<8; zg++){
        uint4 L[8];
        #pragma unroll
        for (int k=0;k<8;k++)
            L[k] = *(const uint4*)(states + ((size_t)(b*64 + zg*8+k)*NH + h)*4096 + e0);
        #pragma unroll
        for (int k=0;k<8;k++){
            int z = zg*8 + k;
            float dec = expf(cs_sh[z]);
            uint4 o;
            o.x = (unsigned)f2bf(S[0]) | ((unsigned)f2bf(S[1])<<16);
            o.y = (unsigned)f2bf(S[2]) | ((unsigned)f2bf(S[3])<<16);
            o.z = (unsigned)f2bf(S[4]) | ((unsigned)f2bf(S[5])<<16);
            o.w = (unsigned)f2bf(S[6]) | ((unsigned)f2bf(S[7])<<16);
            *(uint4*)(states + ((size_t)(b*64 + z)*NH + h)*4096 + e0) = o;
            unsigned a[4] = {L[k].x, L[k].y, L[k].z, L[k].w};
            #pragma unroll
            for (int q=0;q<4;q++){
                float lo = bf2f((unsigned short)(a[q]&0xffff));
                float hi = bf2f((unsigned short)(a[q]>>16));
                S[q*2+0] = fmaf(dec, S[q*2+0], lo);
                S[q*2+1] = fmaf(dec, S[q*2+1], hi);
            }
        }
    }
}

// ---------------------------------------------------------------------------
// y_fused MULTI-HEAD: grid (NH/4, nchunks); block handles 4 heads of one
// chunk.  NGROUPS=1 => B,C and G = C.B^T are HEAD-INVARIANT: staged and
// computed ONCE (was 32x redundant -- 8 of 24 MFMAs per old block).  The
// per-head ea=exp(acs) fold into C (old Ce buffer) is replaced by a second
// accumulator: Y_off_raw = C.Sv^T, scaled by ea[row] in f32 at combine
// (fewer LDS writes, ea applied unrounded).  Per head: stage XT/Sv, build
// score into Bs (reused), 16 MFMAs, combine+write.
// ---------------------------------------------------------------------------
__global__ __launch_bounds__(256)
void y_fused(unsigned short* __restrict__ zxbc,
             const float* __restrict__ dtbuf,
             const unsigned short* __restrict__ entst,
             const float* __restrict__ acsbuf,
             const float* __restrict__ Dvec)
{
    const int hg = blockIdx.x, c = blockIdx.y;
    __shared__ unsigned short Cr[64*72];   // raw C (shared, persists)
    __shared__ unsigned short Bs[64*72];   // raw B for G; then score (per head)
    __shared__ unsigned short XT[64*72];   // x^T  (per head)
    __shared__ unsigned short Sv[64*72];   // entering states (per head)
    __shared__ float acs_sh[64], dt_sh[64], ea_sh[64];
    const int tid = threadIdx.x;
    const size_t row0 = (size_t)(c*64)*ZROW;

    // shared stage: raw C and raw B (vector copies, no transpose)
    {
        const int l  = tid >> 2;
        const int f4 = tid & 3;
        const unsigned short* xr = zxbc + row0 + (size_t)l*ZROW;
        #pragma unroll
        for (int q=0;q<4;q++){
            int col = f4*4 + q*16;
            *(uint2*)&Cr[l*72 + col] = *(const uint2*)(xr + DINNER + DINNER + DSTATE + col);
            *(uint2*)&Bs[l*72 + col] = *(const uint2*)(xr + DINNER + DINNER + col);
        }
    }
    __syncthreads();

    const int wave = tid >> 6, lane = tid & 63;
    const int quad = lane >> 4, l15 = lane & 15;

    // G = C.B^T once (head-invariant); g persists in registers
    f32x4 g[4];
    #pragma unroll
    for (int j=0;j<4;j++) g[j] = (f32x4){0.f,0.f,0.f,0.f};
    #pragma unroll
    for (int ks=0;ks<2;ks++){
        bf16x8 af = *(const bf16x8*)&Cr[(wave*16 + l15)*72 + ks*32 + quad*8];
        #pragma unroll
        for (int j=0;j<4;j++){
            bf16x8 bf = *(const bf16x8*)&Bs[(j*16 + l15)*72 + ks*32 + quad*8];
            g[j] = __builtin_amdgcn_mfma_f32_16x16x32_bf16(af, bf, g[j], 0,0,0);
        }
    }

    for (int hh=0; hh<4; hh++){
        const int h = hg*4 + hh;
        __syncthreads();   // G's Bs reads / prev head's MFMA reads complete
        if (tid < 64){
            float a = acsbuf[((size_t)c*NH + h)*64 + tid];
            acs_sh[tid] = a;
            ea_sh[tid]  = expf(a);
            dt_sh[tid]  = dtbuf[(size_t)(c*64 + tid)*NH + h];
        }
        {
            const int l  = tid >> 2;
            const int f4 = tid & 3;
            const unsigned short* xr = zxbc + row0 + (size_t)l*ZROW;
            const size_t sbase = ((size_t)c*NH + h)*4096;
            #pragma unroll
            for (int q=0;q<4;q++){
                int col = f4*4 + q*16;
                uint2 xv = *(const uint2*)(xr + DINNER + h*HD + col);
                XT[(col+0)*72 + l] = (unsigned short)(xv.x & 0xffff);
                XT[(col+1)*72 + l] = (unsigned short)(xv.x >> 16);
                XT[(col+2)*72 + l] = (unsigned short)(xv.y & 0xffff);
                XT[(col+3)*72 + l] = (unsigned short)(xv.y >> 16);
                *(uint2*)&Sv[l*72 + col] = *(const uint2*)(entst + sbase + (size_t)l*64 + col);
            }
        }
        __syncthreads();   // acs/dt/XT/Sv ready; Bs free for score

        const float Dh = Dvec[h];
        #pragma unroll
        for (int j=0;j<4;j++)
            #pragma unroll
            for (int r=0;r<4;r++){
                int l = wave*16 + quad*4 + r;
                int s = j*16 + l15;
                float v = (s <= l) ? g[j][r]*expf(acs_sh[l]-acs_sh[s])*dt_sh[s] : 0.f;
                if (s == l) v += Dh;
                Bs[l*72 + s] = f2bf(v);
            }
        __syncthreads();   // score visible

        f32x4 y1[4], y2[4];
        #pragma unroll
        for (int j=0;j<4;j++){ y1[j] = (f32x4){0.f,0.f,0.f,0.f}; y2[j] = (f32x4){0.f,0.f,0.f,0.f}; }
        #pragma unroll
        for (int ks=0;ks<2;ks++){
            bf16x8 a1 = *(const bf16x8*)&Bs[(wave*16 + l15)*72 + ks*32 + quad*8];
            bf16x8 a2 = *(const bf16x8*)&Cr[(wave*16 + l15)*72 + ks*32 + quad*8];
            #pragma unroll
            for (int j=0;j<4;j++){
                bf16x8 b1 = *(const bf16x8*)&XT[(j*16 + l15)*72 + ks*32 + quad*8];
                bf16x8 b2 = *(const bf16x8*)&Sv[(j*16 + l15)*72 + ks*32 + quad*8];
                y1[j] = __builtin_amdgcn_mfma_f32_16x16x32_bf16(a1, b1, y1[j], 0,0,0);
                y2[j] = __builtin_amdgcn_mfma_f32_16x16x32_bf16(a2, b2, y2[j], 0,0,0);
            }
        }
        #pragma unroll
        for (int j=0;j<4;j++)
            #pragma unroll
            for (int r=0;r<4;r++){
                int l = wave*16 + quad*4 + r;
                int p = j*16 + l15;
                zxbc[row0 + (size_t)l*ZROW + DINNER + h*HD + p] =
                    f2bf(y1[j][r] + ea_sh[l]*y2[j][r]);
            }
    }
}

// ---------------------------------------------------------------------------
// gate + RMSNorm: y = RMSNorm(Y*silu(z))*w; writes y bf16 over z cols.
// ---------------------------------------------------------------------------
__global__ __launch_bounds__(256)
void gate_norm(unsigned short* __restrict__ zxbc, const float* __restrict__ norm_w)
{
    const int m = blockIdx.x;
    const int tid = threadIdx.x;
    unsigned short* row = zxbc + (size_t)m*ZROW;
    uint4 zv = *(const uint4*)(row + tid*8);
    uint4 yv = *(const uint4*)(row + DINNER + tid*8);
    unsigned zz[4] = {zv.x, zv.y, zv.z, zv.w};
    unsigned yy[4] = {yv.x, yv.y, yv.z, yv.w};
    float g[8];
    float acc = 0.f;
    #pragma unroll
    for (int q=0;q<4;q++){
        float zl = bf2f((unsigned short)(zz[q]&0xffff));
        float zh = bf2f((unsigned short)(zz[q]>>16));
        float yl = bf2f((unsigned short)(yy[q]&0xffff));
        float yh = bf2f((unsigned short)(yy[q]>>16));
        g[q*2+0] = yl * zl * sigm(zl);
        g[q*2+1] = yh * zh * sigm(zh);
        acc += g[q*2]*g[q*2] + g[q*2+1]*g[q*2+1];
    }
    #pragma unroll
    for (int o=32;o>0;o>>=1) acc += __shfl_down(acc, o, 64);
    __shared__ float red[4];
    if ((tid & 63)==0) red[tid>>6] = acc;
    __syncthreads();
    float tot = red[0]+red[1]+red[2]+red[3];
    float scale = rsqrtf(tot * (1.f/2048.f) + 1e-5f);
    const float* nw = norm_w + tid*8;
    float4 w0 = *(const float4*)nw;
    float4 w1 = *(const float4*)(nw+4);
    float Wv[8] = {w0.x,w0.y,w0.z,w0.w,w1.x,w1.y,w1.z,w1.w};
    uint4 ov;
    unsigned ow[4];
    #pragma unroll
    for (int q=0;q<4;q++){
        unsigned short lo = f2bf(g[q*2+0]*scale*Wv[q*2+0]);
        unsigned short hi = f2bf(g[q*2+1]*scale*Wv[q*2+1]);
        ow[q] = (unsigned)lo | ((unsigned)hi<<16);
    }
    ov.x=ow[0]; ov.y=ow[1]; ov.z=ow[2]; ov.w=ow[3];
    *(uint4*)(row + tid*8) = ov;
}

// ---------------------------------------------------------------------------
extern "C" void kernel_launch(void* const* d_in, const int* in_sizes, int n_in,
                              void* d_out, int out_size, void* d_ws, size_t ws_size,
                              hipStream_t stream) {
    const float* u           = (const float*)d_in[0];
    const float* in_proj_w   = (const float*)d_in[1];
    const float* conv_w      = (const float*)d_in[2];
    const float* conv_b      = (const float*)d_in[3];
    const float* init_states = (const float*)d_in[4];
    const float* dt_bias     = (const float*)d_in[5];
    const float* A_log       = (const float*)d_in[6];
    const float* Dv          = (const float*)d_in[7];
    const float* norm_w      = (const float*)d_in[8];
    const float* out_proj_w  = (const float*)d_in[9];
    float* out = (float*)d_out;
    char* wsb = (char*)d_ws;

    // BIG layout (~226 MB): all 4 batches in one pipeline.
    // SMALL layout (~66 MB): per-batch windows (proven envelope).
    const size_t BIG_BYTES = 226197504;
    const bool big = (ws_size >= BIG_BYTES);
    const int nb = big ? BATCH : 1;
    const size_t Mrows = (size_t)nb * LSEQ;          // rows per pipeline pass

    size_t off = 0;
    unsigned short* zxbc    = (unsigned short*)(wsb + off); off += Mrows*ZROW*2;
    unsigned short* statesz = (unsigned short*)(wsb + off);
    unsigned short* ubf     = statesz;               // alias: dead before states written
    off += Mrows/64 * NH*HD*DSTATE*2;                // nb*16.78MB
    unsigned short* wibf    = (unsigned short*)(wsb + off); off += (size_t)NPROJ*DMODEL*2;
    unsigned short* woutbf  = (unsigned short*)(wsb + off); off += (size_t)DMODEL*DINNER*2;
    float*          dtbuf   = (float*)(wsb + off);   off += Mrows*NH*4;
    float*          acsbuf  = (float*)(wsb + off);   off += Mrows/64 * NH*64*4;
    float*          csumbuf = (float*)(wsb + off);   off += Mrows/64 * NH*4;
    unsigned short* halo    = (unsigned short*)(wsb + off); off += Mrows/64 * 3*CONVD*2;

    // weights -> bf16 (once; wibf rows 4256..4351 stay poison, never stored)
    f32_to_bf16<<<dim3((4256*1024/8 + 255)/256), 256, 0, stream>>>(
        in_proj_w, wibf, (size_t)4256*1024);
    f32_to_bf16<<<dim3(1024*2048/8/256), 256, 0, stream>>>(
        out_proj_w, woutbf, (size_t)1024*2048);

    const int npass = big ? 1 : BATCH;
    for (int b=0; b<npass; b++){
        const float* ub   = u   + (size_t)b*LSEQ*DMODEL;
        float*       outb = out + (size_t)b*LSEQ*DMODEL;
        const int mt = (int)(Mrows/128);             // M tiles per pass

        // 0) u -> bf16
        f32_to_bf16<<<dim3(Mrows*DMODEL/8/256), 256, 0, stream>>>(
            ub, ubf, Mrows*DMODEL);
        // 1) merged in_proj (z + xBC + dt) + halo + softplus, grouped swizzle
        gemm_mfma<1><<<dim3((NPROJ/128) * mt), 256, 0, stream>>>(
            ubf, wibf, DMODEL, DMODEL, 0, NPROJ/128, (int)Mrows,
            nullptr, zxbc, dtbuf, dt_bias, halo);
        // 2) causal conv + silu in place
        conv_inplace<<<dim3(9, (unsigned)(Mrows/64)), 256, 0, stream>>>(
            zxbc, halo, conv_w, conv_b);
        // 3) local states (MFMA) + acs/csum, 4 heads per block
        states_intra<<<dim3(NH/4, (unsigned)(Mrows/64)), 256, 0, stream>>>(
            zxbc, dtbuf, A_log, statesz, acsbuf, csumbuf);
        // 4) inter-chunk scan in place (loc -> entering)
        chunk_scan<<<dim3(NH, 2, nb), 256, 0, stream>>>(
            statesz, csumbuf, init_states);
        // 5) fused Y = Y_diag + Y_off + x*D, 4 heads per block (shared B/C/G)
        y_fused<<<dim3(NH/4, (unsigned)(Mrows/64)), 256, 0, stream>>>(
            zxbc, dtbuf, statesz, acsbuf, Dv);
        // 6) gate + RMSNorm -> y bf16 over z cols
        gate_norm<<<dim3((unsigned)Mrows), 256, 0, stream>>>(zxbc, norm_w);
        // 7) out_proj -> out fp32, grouped swizzle
        gemm_mfma<0><<<dim3((DMODEL/128) * mt), 256, 0, stream>>>(
            zxbc, woutbf, DINNER, ZROW, DMODEL, DMODEL/128, (int)Mrows,
            outb, nullptr, nullptr, nullptr, nullptr);
    }
}